// Round 14
// baseline (42.628 us; speedup 1.0000x reference)
//
#include <hip/hip_runtime.h>

// LocallyConnected2d: x(16,3,128,128) f32, W(61,61,64,3,8,8) f32, bias(64,61,61) f32
// out(16,1,488,488) f32; stride 2, kernel 8, no pad; pixel-shuffle r=8 epilogue.
//
// R12: rolling 2-deep prefetch pipeline. 512 blocks (2/CU, 60 KB LDS), 256
// thr, each walks ~7 hw tiles (tile i -> hw = bid + i*512). Double register
// banks (12 W float4 + 6 x float2 + bias) and double f16 LDS buffers. Per
// iteration: issue next tile's 19 loads into the spare bank, counted
// s_waitcnt vmcnt(19) (current tile drained, next stays in flight -> memory
// issue never pauses), convert+LDS-write, lgkmcnt(0) + RAW s_barrier (no
// vmcnt(0) drain), MFMA + store. Compute = validated R6b/R9: rotation-
// swizzled rows (slot=(s8+row&7)%24), 6x mfma_f32_16x16x32_f16,
// C: row(batch)=lk*4+r, col(oc)=lq.

namespace {
constexpr int NHW  = 61 * 61;       // 3721
constexpr int XB   = 3 * 128 * 128;
constexpr int XCC  = 128 * 128;
constexpr int OSTR = 488 * 488;
constexpr int GRID = 512;
}

typedef __fp16   fp16x2 __attribute__((ext_vector_type(2)));
typedef _Float16 half8v __attribute__((ext_vector_type(8)));
typedef float    f32x4  __attribute__((ext_vector_type(4)));

union H8 { fp16x2 p[4]; half8v h; uint4 u; };

__global__ __launch_bounds__(256, 2) void lc2d_kernel(
    const float* __restrict__ xg,   // [16][3][128][128]
    const float* __restrict__ wg,   // [61][61][64][3][8][8]
    const float* __restrict__ bg,   // [64][61][61]
    float* __restrict__ og)         // [16][488][488]
{
    __shared__ __align__(16) _Float16 wlh[2][64 * 192];   // 48 KB
    __shared__ __align__(16) _Float16 xlh[2][16 * 192];   // 12 KB

    const int bid  = blockIdx.x;
    const int t    = threadIdx.x;
    const int lane = t & 63;
    const int wv   = t >> 6;
    const int lq   = lane & 15;         // A row (batch) / B col (oc)
    const int lk   = lane >> 4;         // k-run selector
    const int ocl  = wv * 16 + lq;      // oc 0..63
    const int nt   = 7 + (bid < (NHW - 7 * GRID));   // 137 blocks get 8

    // ---- issue one tile's 19 loads (12 W f4 + 6 x f2 + 1 bias) ----------
    auto issue = [&](float4 (&wr)[12], float2 (&xr)[6], float& bz, int hw)
        __attribute__((always_inline)) {
        const float* wbase = wg + (size_t)hw * 12288;
        #pragma unroll
        for (int it = 0; it < 6; ++it) {
            const int g  = it * 256 + t;
            const int oc = g / 24;
            const int s8 = g - oc * 24;
            const float* src = wbase + oc * 192 + s8 * 8;
            wr[it * 2]     = *reinterpret_cast<const float4*>(src);
            wr[it * 2 + 1] = *reinterpret_cast<const float4*>(src + 4);
        }
        const int hh = hw / 61;
        const int ww = hw - hh * 61;
        const float* xb = xg + hh * 2 * 128 + ww * 2;
        #pragma unroll
        for (int it = 0; it < 6; ++it) {
            const int f  = it * 256 + t;
            const int b  = f / 96;
            const int r  = f - b * 96;
            const int k  = r * 2;
            const int c  = k >> 6;
            const int ii = (k >> 3) & 7;
            const int j  = k & 7;
            xr[it] = *reinterpret_cast<const float2*>(xb + b * XB + c * XCC + ii * 128 + j);
        }
        bz = bg[ocl * NHW + hw];
    };

    // ---- convert one tile's regs -> f16 LDS buffer p --------------------
    auto convw = [&](float4 (&wr)[12], float2 (&xr)[6], int p)
        __attribute__((always_inline)) {
        #pragma unroll
        for (int it = 0; it < 6; ++it) {
            const int g  = it * 256 + t;
            const int oc = g / 24;
            const int s8 = g - oc * 24;
            H8 u;
            u.p[0] = __builtin_amdgcn_cvt_pkrtz(wr[it*2].x,   wr[it*2].y);
            u.p[1] = __builtin_amdgcn_cvt_pkrtz(wr[it*2].z,   wr[it*2].w);
            u.p[2] = __builtin_amdgcn_cvt_pkrtz(wr[it*2+1].x, wr[it*2+1].y);
            u.p[3] = __builtin_amdgcn_cvt_pkrtz(wr[it*2+1].z, wr[it*2+1].w);
            int srot = s8 + (oc & 7); if (srot >= 24) srot -= 24;
            *reinterpret_cast<uint4*>(&wlh[p][oc * 192 + srot * 8]) = u.u;
        }
        #pragma unroll
        for (int it = 0; it < 6; ++it) {
            const int f  = it * 256 + t;
            const int b  = f / 96;
            const int r  = f - b * 96;
            const int s8 = r >> 2;
            const int j  = (r & 3) * 2;
            const fp16x2 pk = __builtin_amdgcn_cvt_pkrtz(xr[it].x, xr[it].y);
            int srot = s8 + (b & 7); if (srot >= 24) srot -= 24;
            union { fp16x2 pp; unsigned u; } cv; cv.pp = pk;
            *reinterpret_cast<unsigned*>(&xlh[p][b * 192 + srot * 8 + j]) = cv.u;
        }
    };

    // ---- MFMA + store for buffer p --------------------------------------
    auto compute = [&](int p, float bz, int hw) __attribute__((always_inline)) {
        const int hh = hw / 61;
        const int ww = hw - hh * 61;
        f32x4 acc = {0.f, 0.f, 0.f, 0.f};
        #pragma unroll
        for (int ks = 0; ks < 6; ++ks) {
            const int slog = ks * 4 + lk;
            int sa = slog + (lq & 7);  if (sa >= 24) sa -= 24;
            int sb = slog + (ocl & 7); if (sb >= 24) sb -= 24;
            const half8v av = *reinterpret_cast<const half8v*>(&xlh[p][lq  * 192 + sa * 8]);
            const half8v bv = *reinterpret_cast<const half8v*>(&wlh[p][ocl * 192 + sb * 8]);
            acc = __builtin_amdgcn_mfma_f32_16x16x32_f16(av, bv, acc, 0, 0, 0);
        }
        float* ob = og + (hh * 8 + (ocl >> 3)) * 488 + (ww * 8 + (ocl & 7));
        #pragma unroll
        for (int r = 0; r < 4; ++r) {
            const int b = lk * 4 + r;
            ob[(size_t)b * OSTR] = acc[r] + bz;
        }
    };

    float4 wrA[12], wrB[12];
    float2 xrA[6],  xrB[6];
    float  bzA = 0.f, bzB = 0.f;

    issue(wrA, xrA, bzA, bid);          // prologue: tile 0 -> bank A
    int i = 0;
    while (true) {
        // ---- bank A iteration ----
        {
            if (i + 1 < nt) {
                issue(wrB, xrB, bzB, bid + (i + 1) * GRID);
                asm volatile("s_waitcnt vmcnt(19)" ::: "memory");
            } else {
                asm volatile("s_waitcnt vmcnt(4)" ::: "memory");
            }
            __builtin_amdgcn_sched_barrier(0);
            convw(wrA, xrA, i & 1);
            asm volatile("s_waitcnt lgkmcnt(0)" ::: "memory");
            __builtin_amdgcn_s_barrier();
            __builtin_amdgcn_sched_barrier(0);
            compute(i & 1, bzA, bid + i * GRID);
            ++i; if (i >= nt) break;
        }
        // ---- bank B iteration ----
        {
            if (i + 1 < nt) {
                issue(wrA, xrA, bzA, bid + (i + 1) * GRID);
                asm volatile("s_waitcnt vmcnt(19)" ::: "memory");
            } else {
                asm volatile("s_waitcnt vmcnt(4)" ::: "memory");
            }
            __builtin_amdgcn_sched_barrier(0);
            convw(wrB, xrB, i & 1);
            asm volatile("s_waitcnt lgkmcnt(0)" ::: "memory");
            __builtin_amdgcn_s_barrier();
            __builtin_amdgcn_sched_barrier(0);
            compute(i & 1, bzB, bid + i * GRID);
            ++i; if (i >= nt) break;
        }
    }
}

extern "C" void kernel_launch(void* const* d_in, const int* in_sizes, int n_in,
                              void* d_out, int out_size, void* d_ws, size_t ws_size,
                              hipStream_t stream) {
    const float* x    = (const float*)d_in[0];
    const float* W    = (const float*)d_in[1];
    const float* bias = (const float*)d_in[2];
    float* out        = (float*)d_out;
    lc2d_kernel<<<dim3(GRID), dim3(256), 0, stream>>>(x, W, bias, out);
}

// Round 15
// 39.303 us; speedup vs baseline: 1.0846x; 1.0846x over previous
//
#include <hip/hip_runtime.h>

// LocallyConnected2d: x(16,3,128,128) f32, W(61,61,64,3,8,8) f32, bias(64,61,61) f32
// out(16,1,488,488) f32; stride 2, kernel 8, no pad; pixel-shuffle r=8 epilogue.
//
// R13: R9 (best, 39.7us) at 6 blocks/CU (24 waves/CU) via launch_bounds
// (256,6). To fit the 85-VGPR cap the W issue is split into two 6-float4
// half-batches, interleaved so a half is always in flight under the other's
// convert: x loads -> W-A loads -> x convert (waits x only) -> W-B loads ->
// W-A convert -> W-B convert -> barrier -> MFMA. Compute identical to
// validated R6b/R9: rotation-swizzled rows (slot=(s8+row&7)%24, 2-way free
// ds_read_b128), 6x mfma_f32_16x16x32_f16, C: row(batch)=lk*4+r, col(oc)=lq.

namespace {
constexpr int NHW  = 61 * 61;       // 3721
constexpr int XB   = 3 * 128 * 128;
constexpr int XCC  = 128 * 128;
constexpr int OSTR = 488 * 488;
}

typedef __fp16   fp16x2 __attribute__((ext_vector_type(2)));
typedef _Float16 half8v __attribute__((ext_vector_type(8)));
typedef float    f32x4  __attribute__((ext_vector_type(4)));

union H8 { fp16x2 p[4]; half8v h; uint4 u; };

__global__ __launch_bounds__(256, 6) void lc2d_kernel(
    const float* __restrict__ xg,   // [16][3][128][128]
    const float* __restrict__ wg,   // [61][61][64][3][8][8]
    const float* __restrict__ bg,   // [64][61][61]
    float* __restrict__ og)         // [16][488][488]
{
    __shared__ __align__(16) _Float16 wlh[64 * 192];   // 24 KB
    __shared__ __align__(16) _Float16 xlh[16 * 192];   //  6 KB

    const int hw   = blockIdx.x;
    const int h    = hw / 61;
    const int w    = hw - h * 61;
    const int t    = threadIdx.x;
    const int lane = t & 63;
    const int wv   = t >> 6;

    const float* wbase = wg + (size_t)hw * (64 * 192);
    const float* xb    = xg + (h * 2) * 128 + (w * 2);

    // ---- phase 1a: x stage loads (oldest in FIFO -> retire first) -------
    float2 xr[6];
    #pragma unroll
    for (int it = 0; it < 6; ++it) {
        const int f  = it * 256 + t;
        const int b  = f / 96;
        const int r  = f - b * 96;
        const int k  = r * 2;
        const int c  = k >> 6;              // channel
        const int i  = (k >> 3) & 7;        // kernel row
        const int j  = k & 7;               // within-run offset (even)
        xr[it] = *reinterpret_cast<const float2*>(xb + b * XB + c * XCC + i * 128 + j);
    }
    // ---- phase 1b: W half-A loads (6 float4, stay in flight) ------------
    float4 wrA[6];
    #pragma unroll
    for (int it = 0; it < 3; ++it) {
        const int g  = it * 256 + t;
        const int oc = g / 24;
        const int s8 = g - oc * 24;
        const float* src = wbase + oc * 192 + s8 * 8;
        wrA[it * 2]     = *reinterpret_cast<const float4*>(src);
        wrA[it * 2 + 1] = *reinterpret_cast<const float4*>(src + 4);
    }
    __builtin_amdgcn_sched_barrier(0);

    // ---- phase 2: x convert + LDS write (waits only on x loads) ---------
    #pragma unroll
    for (int it = 0; it < 6; ++it) {
        const int f  = it * 256 + t;
        const int b  = f / 96;
        const int r  = f - b * 96;
        const int s8 = r >> 2;
        const int j  = (r & 3) * 2;
        const fp16x2 pk = __builtin_amdgcn_cvt_pkrtz(xr[it].x, xr[it].y);
        int srot = s8 + (b & 7); if (srot >= 24) srot -= 24;
        union { fp16x2 p; unsigned u; } cv; cv.p = pk;
        *reinterpret_cast<unsigned*>(&xlh[b * 192 + srot * 8 + j]) = cv.u;
    }
    __builtin_amdgcn_sched_barrier(0);

    // ---- phase 3: W half-B loads (in flight under half-A convert) -------
    float4 wrB[6];
    #pragma unroll
    for (int it = 3; it < 6; ++it) {
        const int g  = it * 256 + t;
        const int oc = g / 24;
        const int s8 = g - oc * 24;
        const float* src = wbase + oc * 192 + s8 * 8;
        wrB[(it - 3) * 2]     = *reinterpret_cast<const float4*>(src);
        wrB[(it - 3) * 2 + 1] = *reinterpret_cast<const float4*>(src + 4);
    }
    __builtin_amdgcn_sched_barrier(0);

    // ---- phase 4: W half-A convert + LDS write --------------------------
    #pragma unroll
    for (int it = 0; it < 3; ++it) {
        const int g  = it * 256 + t;
        const int oc = g / 24;
        const int s8 = g - oc * 24;
        H8 u;
        u.p[0] = __builtin_amdgcn_cvt_pkrtz(wrA[it*2].x,   wrA[it*2].y);
        u.p[1] = __builtin_amdgcn_cvt_pkrtz(wrA[it*2].z,   wrA[it*2].w);
        u.p[2] = __builtin_amdgcn_cvt_pkrtz(wrA[it*2+1].x, wrA[it*2+1].y);
        u.p[3] = __builtin_amdgcn_cvt_pkrtz(wrA[it*2+1].z, wrA[it*2+1].w);
        int srot = s8 + (oc & 7); if (srot >= 24) srot -= 24;
        *reinterpret_cast<uint4*>(&wlh[oc * 192 + srot * 8]) = u.u;
    }
    // ---- phase 5: W half-B convert + LDS write --------------------------
    #pragma unroll
    for (int it = 3; it < 6; ++it) {
        const int g  = it * 256 + t;
        const int oc = g / 24;
        const int s8 = g - oc * 24;
        H8 u;
        u.p[0] = __builtin_amdgcn_cvt_pkrtz(wrB[(it-3)*2].x,   wrB[(it-3)*2].y);
        u.p[1] = __builtin_amdgcn_cvt_pkrtz(wrB[(it-3)*2].z,   wrB[(it-3)*2].w);
        u.p[2] = __builtin_amdgcn_cvt_pkrtz(wrB[(it-3)*2+1].x, wrB[(it-3)*2+1].y);
        u.p[3] = __builtin_amdgcn_cvt_pkrtz(wrB[(it-3)*2+1].z, wrB[(it-3)*2+1].w);
        int srot = s8 + (oc & 7); if (srot >= 24) srot -= 24;
        *reinterpret_cast<uint4*>(&wlh[oc * 192 + srot * 8]) = u.u;
    }
    __syncthreads();

    // ---- phase 6: MFMA (wave wv -> ocs wv*16..+16) ----------------------
    const int lq  = lane & 15;          // A row (batch) / B col (oc)
    const int lk  = lane >> 4;          // k-run selector
    const int ocl = wv * 16 + lq;

    f32x4 acc = {0.f, 0.f, 0.f, 0.f};
    #pragma unroll
    for (int ks = 0; ks < 6; ++ks) {
        const int slog = ks * 4 + lk;
        int sa = slog + (lq & 7);   if (sa >= 24) sa -= 24;
        int sb = slog + (ocl & 7);  if (sb >= 24) sb -= 24;
        const half8v av = *reinterpret_cast<const half8v*>(&xlh[lq  * 192 + sa * 8]);
        const half8v bv = *reinterpret_cast<const half8v*>(&wlh[ocl * 192 + sb * 8]);
        acc = __builtin_amdgcn_mfma_f32_16x16x32_f16(av, bv, acc, 0, 0, 0);
    }

    // ---- epilogue: bias + pixel-shuffle store ---------------------------
    const float bz = bg[ocl * NHW + hw];
    float* ob = og + (h * 8 + (ocl >> 3)) * 488 + (w * 8 + (ocl & 7));
    #pragma unroll
    for (int r = 0; r < 4; ++r) {
        const int b = lk * 4 + r;       // batch = C row
        ob[(size_t)b * OSTR] = acc[r] + bz;
    }
}

extern "C" void kernel_launch(void* const* d_in, const int* in_sizes, int n_in,
                              void* d_out, int out_size, void* d_ws, size_t ws_size,
                              hipStream_t stream) {
    const float* x    = (const float*)d_in[0];
    const float* W    = (const float*)d_in[1];
    const float* bias = (const float*)d_in[2];
    float* out        = (float*)d_out;
    lc2d_kernel<<<dim3(NHW), dim3(256), 0, stream>>>(x, W, bias, out);
}